// Round 6
// baseline (604.282 us; speedup 1.0000x reference)
//
#include <hip/hip_runtime.h>

// Geo-FFNO forward: factored Fourier (DFT -> per-mode complex mix -> iDFT, 16 modes)
// + fused FFN (Linear 128->512, ReLU, Linear 512->128, +bias, LayerNorm).
// B=16, M=N=128, D=I=O=128, NM=16, H=512.
//
// R6: k_ffn software-pipelined (1-wave blocks kept): GEMM2 weight frags issued at
// chunk top (covered by GEMM1 MFMAs), next chunk's GEMM1 frags issued under GEMM2,
// batched stage loads, LDS pads retuned (134/38) for ~2-way banks.

#define LN_EPS 1e-5f
#define NMODES 16
#define FROW 4096     // per-row F/f size: 16k * 2 * 128
#define HROW 16384    // per (b,m) h row: 128*128

typedef __attribute__((ext_vector_type(8))) short short8;
typedef __attribute__((ext_vector_type(8))) ushort ushort8;
typedef __attribute__((ext_vector_type(4))) short short4v;
typedef __attribute__((ext_vector_type(4))) float f32x4;

__device__ __forceinline__ ushort f2bf(float f) {
    unsigned u = __float_as_uint(f);
    unsigned r = (u + 0x7FFFu + ((u >> 16) & 1u)) >> 16;   // RNE
    return (ushort)r;
}
__device__ __forceinline__ float bf2f(ushort h) {
    return __uint_as_float(((unsigned)h) << 16);
}

// ---------------- tables ----------------
__global__ void k_setup(float* __restrict__ Tc, float* __restrict__ Ts,
                        float* __restrict__ IT) {
    const float invs = 0.08838834764831845f;  // 1/sqrt(128)
    for (int idx = threadIdx.x; idx < NMODES * 128; idx += blockDim.x) {
        int k = idx >> 7, n = idx & 127;
        int p = (k * n) & 127;                 // periodic reduction
        float th = (float)p * (6.283185307179586f / 128.0f);
        float c = cosf(th), s = sinf(th);
        Tc[idx] = c * invs;                    // forward: (1/sqrtN) cos
        Ts[idx] = -s * invs;                   // forward: -(1/sqrtN) sin
        float ck = (k == 0) ? invs : 2.0f * invs;
        IT[n * 32 + 2 * k]     = ck * c;       // inverse: c_k cos
        IT[n * 32 + 2 * k + 1] = -ck * s;      // inverse: -c_k sin
    }
}

// ---------------- packed complex-mix weights, transposed, bf16 hi/lo ----------------
// Layout: [k][op][ip]; value(ip,op): ip<128: (op<128? re : im); ip>=128: (op<128? -im : re)
__global__ void k_wpack(const float* __restrict__ w, ushort* __restrict__ Wph,
                        ushort* __restrict__ Wpl) {
    int idx = blockIdx.x * 256 + threadIdx.x;  // 16*256*256 = 1,048,576
    int k  = idx >> 16;
    int op = (idx >> 8) & 255;
    int ip = idx & 255;
    int i = ip & 127, o = op & 127;
    const float* base = w + (((i << 7) | o) * NMODES + k) * 2;
    float re = base[0], im = base[1];
    float v = (ip < 128) ? ((op < 128) ? re : im)
                         : ((op < 128) ? -im : re);
    ushort hi = f2bf(v);
    ushort lo = f2bf(v - bf2f(hi));
    Wph[idx] = hi;
    Wpl[idx] = lo;
}

// ---------------- bf16 FFN weights (once) ----------------
// w0t[h][k] = w0[k][h]  (512x128 bf16); w1t[o][h] = w1[h][o]  (128x512 bf16)
__global__ __launch_bounds__(256) void k_wcvt(const float* __restrict__ w0,
        const float* __restrict__ w1, ushort* __restrict__ w0t,
        ushort* __restrict__ w1t) {
    int idx = blockIdx.x * 256 + threadIdx.x;   // 65536
    int h = idx >> 7, k = idx & 127;
    w0t[idx] = f2bf(w0[k * 512 + h]);
    int o = idx >> 9, hh = idx & 511;
    w1t[idx] = f2bf(w1[hh * 128 + o]);
}

// ---------------- truncated forward DFT ----------------
__global__ __launch_bounds__(128) void k_fft(const float* __restrict__ x,
        const float* __restrict__ Tc, const float* __restrict__ Ts,
        float* __restrict__ F, int mode) {
    __shared__ float Tc_s[NMODES * 128];
    __shared__ float Ts_s[NMODES * 128];
    for (int e = threadIdx.x; e < NMODES * 128; e += 128) {
        Tc_s[e] = Tc[e];
        Ts_s[e] = Ts[e];
    }
    __syncthreads();
    int row = blockIdx.x;
    int base, ts;
    if (mode == 0) { base = row * HROW; ts = 128; }
    else { base = (row >> 7) * 2097152 + (row & 127) * 128; ts = 16384; }
    int i = threadIdx.x;
    float re[NMODES], im[NMODES];
#pragma unroll
    for (int k = 0; k < NMODES; ++k) { re[k] = 0.f; im[k] = 0.f; }
    for (int tb = 0; tb < 32; ++tb) {
        int t0 = tb * 4;
        float xv0 = x[base + (t0 + 0) * ts + i];
        float xv1 = x[base + (t0 + 1) * ts + i];
        float xv2 = x[base + (t0 + 2) * ts + i];
        float xv3 = x[base + (t0 + 3) * ts + i];
#pragma unroll
        for (int k = 0; k < NMODES; ++k) {
            f32x4 c4 = *(const f32x4*)&Tc_s[k * 128 + t0];
            f32x4 s4 = *(const f32x4*)&Ts_s[k * 128 + t0];
            re[k] += xv0 * c4[0] + xv1 * c4[1] + xv2 * c4[2] + xv3 * c4[3];
            im[k] += xv0 * s4[0] + xv1 * s4[1] + xv2 * s4[2] + xv3 * s4[3];
        }
    }
    float* outp = F + row * FROW;
#pragma unroll
    for (int k = 0; k < NMODES; ++k) {
        outp[k * 256 + i]       = re[k];
        outp[k * 256 + 128 + i] = im[k];
    }
}

// ---------------- per-mode channel mix, bf16x3 MFMA (in-place safe) ----------------
__global__ __launch_bounds__(256) void k_mixm(const float* __restrict__ A,
        const ushort* __restrict__ Wph, const ushort* __restrict__ Wpl,
        float* __restrict__ outF) {
    __shared__ ushort Ah[32 * 264];
    __shared__ ushort Al[32 * 264];
    int tid = threadIdx.x;
    int kt = blockIdx.x & 15;
    int bm0 = (blockIdx.x >> 4) * 32;
    {
        int row = tid >> 3, cg = tid & 7;
        const float* arow = A + (bm0 + row) * FROW + kt * 256 + cg * 32;
        ushort* ah = &Ah[row * 264 + cg * 32];
        ushort* al = &Al[row * 264 + cg * 32];
#pragma unroll
        for (int j = 0; j < 8; ++j) {
            f32x4 v = *(const f32x4*)(arow + j * 4);
            short4v h4, l4;
#pragma unroll
            for (int q = 0; q < 4; ++q) {
                ushort h = f2bf(v[q]);
                h4[q] = (short)h;
                l4[q] = (short)f2bf(v[q] - bf2f(h));
            }
            *(short4v*)(ah + j * 4) = h4;
            *(short4v*)(al + j * 4) = l4;
        }
    }
    __syncthreads();
    int lane = tid & 63, wid = tid >> 6;
    int frow = lane & 15, fk8 = (lane >> 4) * 8, fr4 = (lane >> 4) * 4;
    f32x4 acc[2][4];
#pragma unroll
    for (int a = 0; a < 2; ++a)
#pragma unroll
        for (int c = 0; c < 4; ++c) acc[a][c] = {0.f, 0.f, 0.f, 0.f};
    const ushort* wph = Wph + kt * 65536;
    const ushort* wpl = Wpl + kt * 65536;
#pragma unroll
    for (int kk = 0; kk < 8; ++kk) {
        short8 ah0 = *(const short8*)&Ah[(frow)      * 264 + kk * 32 + fk8];
        short8 ah1 = *(const short8*)&Ah[(16 + frow) * 264 + kk * 32 + fk8];
        short8 al0 = *(const short8*)&Al[(frow)      * 264 + kk * 32 + fk8];
        short8 al1 = *(const short8*)&Al[(16 + frow) * 264 + kk * 32 + fk8];
#pragma unroll
        for (int tc = 0; tc < 4; ++tc) {
            int op = wid * 64 + tc * 16 + frow;
            int base = op * 256 + kk * 32 + fk8;
            short8 wh = *(const short8*)&wph[base];
            short8 wl = *(const short8*)&wpl[base];
            acc[0][tc] = __builtin_amdgcn_mfma_f32_16x16x32_bf16(ah0, wh, acc[0][tc], 0, 0, 0);
            acc[0][tc] = __builtin_amdgcn_mfma_f32_16x16x32_bf16(ah0, wl, acc[0][tc], 0, 0, 0);
            acc[0][tc] = __builtin_amdgcn_mfma_f32_16x16x32_bf16(al0, wh, acc[0][tc], 0, 0, 0);
            acc[1][tc] = __builtin_amdgcn_mfma_f32_16x16x32_bf16(ah1, wh, acc[1][tc], 0, 0, 0);
            acc[1][tc] = __builtin_amdgcn_mfma_f32_16x16x32_bf16(ah1, wl, acc[1][tc], 0, 0, 0);
            acc[1][tc] = __builtin_amdgcn_mfma_f32_16x16x32_bf16(al1, wh, acc[1][tc], 0, 0, 0);
        }
    }
#pragma unroll
    for (int tr = 0; tr < 2; ++tr)
#pragma unroll
        for (int tc = 0; tc < 4; ++tc)
#pragma unroll
            for (int r = 0; r < 4; ++r)
                outF[(bm0 + tr * 16 + fr4 + r) * FROW + kt * 256 + wid * 64 + tc * 16 + frow]
                    = acc[tr][tc][r];
}

// ---------------- inverse DFT ----------------
// mode 0: contiguous bf16 write in the branch's own layout: obf[row*16384 + t*128 + o]
// mode 1 (fallback y): f32 h32[row*HROW + ...] = acc
// mode 2 (fallback x): RMW scatter: hbfs[ix] = bf16(h32[ix] + acc)
__global__ __launch_bounds__(256) void k_icdft(const float* __restrict__ f,
        const float* __restrict__ IT, ushort* __restrict__ obf,
        float* __restrict__ h32, ushort* __restrict__ hbfs, int mode) {
    __shared__ float IT_s[128 * 32];
    __shared__ float f_s[32 * 128];
    int row = blockIdx.x;
    for (int e = threadIdx.x; e < 4096; e += 256) {
        IT_s[e] = IT[e];
        f_s[e]  = f[row * FROW + e];
    }
    __syncthreads();
    int o = threadIdx.x & 127, nh = threadIdx.x >> 7;
    for (int nb = 0; nb < 8; ++nb) {
        int n0 = nh * 64 + nb * 8;
        float acc[8];
#pragma unroll
        for (int j = 0; j < 8; ++j) acc[j] = 0.f;
#pragma unroll
        for (int kpb = 0; kpb < 8; ++kpb) {
            int kp0 = kpb * 4;
            float f0 = f_s[kp0 * 128 + o];
            float f1v = f_s[kp0 * 128 + 128 + o];
            float f2v = f_s[kp0 * 128 + 256 + o];
            float f3v = f_s[kp0 * 128 + 384 + o];
#pragma unroll
            for (int j = 0; j < 8; ++j) {
                f32x4 it = *(const f32x4*)&IT_s[(n0 + j) * 32 + kp0];
                acc[j] += f0 * it[0] + f1v * it[1] + f2v * it[2] + f3v * it[3];
            }
        }
        if (mode == 0) {
#pragma unroll
            for (int j = 0; j < 8; ++j)
                obf[row * HROW + (n0 + j) * 128 + o] = f2bf(acc[j]);
        } else if (mode == 1) {
#pragma unroll
            for (int j = 0; j < 8; ++j)
                h32[row * HROW + (n0 + j) * 128 + o] = acc[j];
        } else {
#pragma unroll
            for (int j = 0; j < 8; ++j) {
                int ix = (row >> 7) * 2097152 + (row & 127) * 128 + o + (n0 + j) * 16384;
                hbfs[ix] = f2bf(h32[ix] + acc[j]);
            }
        }
    }
}

// ---------------- fused FFN + LayerNorm: 1-wave blocks, pipelined ----------------
// Each 64-lane wave owns 64 rows. 16 chunks of 32 hidden:
//   [issue b2(ch)] -> GEMM1 (covered) -> h1 -> [issue bfr(ch+1)] -> GEMM2 (covered).
__global__ __launch_bounds__(64, 2) void k_ffn(const ushort* __restrict__ hy,
        const ushort* __restrict__ hx, const ushort* __restrict__ hbfs,
        float* __restrict__ out,
        const ushort* __restrict__ w0t, const float* __restrict__ b0,
        const ushort* __restrict__ w1t, const float* __restrict__ b1,
        const float* __restrict__ g, const float* __restrict__ bb, int two) {
    __shared__ __align__(16) ushort h_s[64 * 134];   // 17152 B (~2-way banks)
    __shared__ __align__(16) ushort h1_s[64 * 38];   //  4864 B (~2-way banks)
    int lane = threadIdx.x;
    int R0 = blockIdx.x * 64;

    if (two) {
        int b = R0 >> 14, m = (R0 >> 7) & 127, n0 = R0 & 127;
        const ushort* hyp = hy + (size_t)R0 * 128;
        const ushort* hxp = hx + (size_t)b * 2097152 + (size_t)n0 * 16384 + m * 128;
#pragma unroll
        for (int half = 0; half < 2; ++half) {
            ushort8 ay[8], ax[8];
#pragma unroll
            for (int i = 0; i < 8; ++i) {      // issue 16 loads back-to-back
                int e = lane + (half * 8 + i) * 64;
                int rl = e >> 4, c8 = (e & 15) * 8;
                ay[i] = *(const ushort8*)&hyp[rl * 128 + c8];
                ax[i] = *(const ushort8*)&hxp[rl * 16384 + c8];
            }
#pragma unroll
            for (int i = 0; i < 8; ++i) {
                int e = lane + (half * 8 + i) * 64;
                int rl = e >> 4, c8 = (e & 15) * 8;
                ushort8 t;
#pragma unroll
                for (int j = 0; j < 8; ++j) t[j] = f2bf(bf2f(ay[i][j]) + bf2f(ax[i][j]));
                *(ushort8*)&h_s[rl * 134 + c8] = t;
            }
        }
    } else {
#pragma unroll
        for (int i = 0; i < 16; ++i) {
            int e = lane + i * 64;
            int rl = e >> 4, c8 = (e & 15) * 8;
            *(ushort8*)&h_s[rl * 134 + c8] =
                *(const ushort8*)&hbfs[(size_t)(R0 + rl) * 128 + c8];
        }
    }
    __syncthreads();   // single wave: cheap

    int frow = lane & 15, qg = lane >> 4;
    int fk8 = qg * 8, fr4 = qg * 4;

    f32x4 acc2[4][8];
#pragma unroll
    for (int a = 0; a < 4; ++a)
#pragma unroll
        for (int c = 0; c < 8; ++c) acc2[a][c] = {0.f, 0.f, 0.f, 0.f};

    // prologue: GEMM1 weight frags for chunk 0
    short8 bfr[2][4];
#pragma unroll
    for (int tc2 = 0; tc2 < 2; ++tc2)
#pragma unroll
        for (int kk = 0; kk < 4; ++kk)
            bfr[tc2][kk] = *(const short8*)&w0t[(tc2 * 16 + frow) * 128 + kk * 32 + fk8];

#pragma unroll 1
    for (int ch = 0; ch < 16; ++ch) {
        // issue GEMM2 weight frags now; GEMM1 covers their latency
        short8 b2[8];
#pragma unroll
        for (int tc = 0; tc < 8; ++tc)
            b2[tc] = *(const short8*)&w1t[(tc * 16 + frow) * 512 + ch * 32 + fk8];
        float b0v0 = b0[ch * 32 + frow];
        float b0v1 = b0[ch * 32 + 16 + frow];

        // ---- GEMM1: 64 rows x 32 hidden, K=128 (two tr-groups) ----
#pragma unroll
        for (int g2 = 0; g2 < 2; ++g2) {
            f32x4 acc1[2][2];
#pragma unroll
            for (int a = 0; a < 2; ++a)
#pragma unroll
                for (int c = 0; c < 2; ++c) acc1[a][c] = {0.f, 0.f, 0.f, 0.f};
#pragma unroll
            for (int kk = 0; kk < 4; ++kk)
#pragma unroll
                for (int t2 = 0; t2 < 2; ++t2) {
                    int tr = g2 * 2 + t2;
                    short8 av = *(const short8*)&h_s[(tr * 16 + frow) * 134 + kk * 32 + fk8];
                    acc1[t2][0] = __builtin_amdgcn_mfma_f32_16x16x32_bf16(
                        av, bfr[0][kk], acc1[t2][0], 0, 0, 0);
                    acc1[t2][1] = __builtin_amdgcn_mfma_f32_16x16x32_bf16(
                        av, bfr[1][kk], acc1[t2][1], 0, 0, 0);
                }
#pragma unroll
            for (int t2 = 0; t2 < 2; ++t2)
#pragma unroll
                for (int r = 0; r < 4; ++r) {
                    int rowl = (g2 * 2 + t2) * 16 + fr4 + r;
                    h1_s[rowl * 38 + frow] =
                        f2bf(fmaxf(acc1[t2][0][r] + b0v0, 0.f));
                    h1_s[rowl * 38 + 16 + frow] =
                        f2bf(fmaxf(acc1[t2][1][r] + b0v1, 0.f));
                }
        }

        // prefetch next chunk's GEMM1 frags; GEMM2 covers their latency
        if (ch < 15) {
#pragma unroll
            for (int tc2 = 0; tc2 < 2; ++tc2)
#pragma unroll
                for (int kk = 0; kk < 4; ++kk)
                    bfr[tc2][kk] = *(const short8*)
                        &w0t[((ch + 1) * 32 + tc2 * 16 + frow) * 128 + kk * 32 + fk8];
        }

        // ---- GEMM2 K-step: 64 rows x 128 out, K=32 ----
#pragma unroll
        for (int tr = 0; tr < 4; ++tr) {
            short8 a2 = *(const short8*)&h1_s[(tr * 16 + frow) * 38 + fk8];
#pragma unroll
            for (int tc = 0; tc < 8; ++tc)
                acc2[tr][tc] = __builtin_amdgcn_mfma_f32_16x16x32_bf16(
                    a2, b2[tc], acc2[tr][tc], 0, 0, 0);
        }
    }

    // ---- epilogue: +b1, in-register LN, direct stores ----
    float b1v[8], gv[8], bv[8];
#pragma unroll
    for (int tc = 0; tc < 8; ++tc) {
        int o = tc * 16 + frow;
        b1v[tc] = b1[o]; gv[tc] = g[o]; bv[tc] = bb[o];
    }
#pragma unroll
    for (int tr = 0; tr < 4; ++tr)
#pragma unroll
        for (int r = 0; r < 4; ++r) {
            float s = 0.f, qq = 0.f;
#pragma unroll
            for (int tc = 0; tc < 8; ++tc) {
                float v = acc2[tr][tc][r] + b1v[tc];
                acc2[tr][tc][r] = v;
                s += v; qq += v * v;
            }
            s += __shfl_xor(s, 1); qq += __shfl_xor(qq, 1);
            s += __shfl_xor(s, 2); qq += __shfl_xor(qq, 2);
            s += __shfl_xor(s, 4); qq += __shfl_xor(qq, 4);
            s += __shfl_xor(s, 8); qq += __shfl_xor(qq, 8);
            float mu = s * (1.0f / 128.0f);
            float var = qq * (1.0f / 128.0f) - mu * mu;
            float rs = rsqrtf(fmaxf(var, 0.f) + LN_EPS);
            float* orow = &out[(size_t)(R0 + tr * 16 + fr4 + r) * 128];
#pragma unroll
            for (int tc = 0; tc < 8; ++tc)
                orow[tc * 16 + frow] = (acc2[tr][tc][r] - mu) * rs * gv[tc] + bv[tc];
        }
}

extern "C" void kernel_launch(void* const* d_in, const int* in_sizes, int n_in,
                              void* d_out, int out_size, void* d_ws, size_t ws_size,
                              hipStream_t stream) {
    (void)in_sizes; (void)n_in; (void)out_size;
    const float* x   = (const float*)d_in[0];
    const float* w1  = (const float*)d_in[1];
    const float* w2  = (const float*)d_in[2];
    const float* fw0 = (const float*)d_in[3];
    const float* fb0 = (const float*)d_in[4];
    const float* fw1 = (const float*)d_in[5];
    const float* fb1 = (const float*)d_in[6];
    const float* lng = (const float*)d_in[7];
    const float* lnb = (const float*)d_in[8];
    float* out = (float*)d_out;

    char* ws = (char*)d_ws;
    float*  Tc  = (float*)(ws);
    float*  Ts  = (float*)(ws + 8192);
    float*  IT  = (float*)(ws + 16384);
    ushort* Wph = (ushort*)(ws + 32768);                  // 2 MB
    ushort* Wpl = (ushort*)(ws + 32768 + 2097152);        // 2 MB
    ushort* w0t = (ushort*)(ws + 4227072);                // 128 KB
    ushort* w1t = (ushort*)(ws + 4358144);                // 128 KB
    float*  buf0 = (float*)(ws + 4489216);                // F/f (33.5 MB, in-place mix)
    ushort* hy   = (ushort*)(ws + 38043648);              // 67 MB
    ushort* hx   = (ushort*)(ws + 105152512);             // 67 MB
    const size_t need_two = 172261376ull;
    int two = (ws_size >= need_two) ? 1 : 0;
    // fallback single-buffer: hbfs at the hy slot (needs 105.2 MB)
    ushort* hbfs = hy;

    k_setup<<<1, 256, 0, stream>>>(Tc, Ts, IT);
    k_wcvt <<<256, 256, 0, stream>>>(fw0, fw1, w0t, w1t);

    // y-branch: DFT over n, mix with w1, inverse over n -> hy[b,m,n,o] bf16
    k_wpack<<<4096, 256, 0, stream>>>(w1, Wph, Wpl);
    k_fft  <<<2048, 128, 0, stream>>>(x, Tc, Ts, buf0, 0);
    k_mixm <<<1024, 256, 0, stream>>>(buf0, Wph, Wpl, buf0);
    if (two) k_icdft<<<2048, 256, 0, stream>>>(buf0, IT, hy, out, hbfs, 0);
    else     k_icdft<<<2048, 256, 0, stream>>>(buf0, IT, hy, out, hbfs, 1);

    // x-branch: DFT over m, mix with w2, inverse over m -> hx[b,n,m,o] bf16
    k_wpack<<<4096, 256, 0, stream>>>(w2, Wph, Wpl);
    k_fft  <<<2048, 128, 0, stream>>>(x, Tc, Ts, buf0, 1);
    k_mixm <<<1024, 256, 0, stream>>>(buf0, Wph, Wpl, buf0);
    if (two) k_icdft<<<2048, 256, 0, stream>>>(buf0, IT, hx, out, hbfs, 0);
    else     k_icdft<<<2048, 256, 0, stream>>>(buf0, IT, hx, out, hbfs, 2);

    // fused FFN + LayerNorm -> d_out (1-wave blocks, pipelined)
    k_ffn<<<4096, 64, 0, stream>>>(hy, hx, hbfs, out, w0t, fb0, w1t, fb1, lng, lnb, two);
}

// Round 7
// 549.340 us; speedup vs baseline: 1.1000x; 1.1000x over previous
//
#include <hip/hip_runtime.h>

// Geo-FFNO forward: factored Fourier (DFT -> per-mode complex mix -> iDFT, 16 modes)
// + fused FFN (Linear 128->512, ReLU, Linear 512->128, +bias, LayerNorm).
// B=16, M=N=128, D=I=O=128, NM=16, H=512.
//
// R7: (a) icdft-x fuses the branch sum (reads hy, writes pre-summed hsum bf16),
//     so k_ffn stages ONE buffer with a pure copy. (b) k_ffn LDS cut to exactly
//     20480 B via XOR-swizzled h_s[64][128] / h1[64][32] (no pads) -> 8 blocks/CU
//     -> 2 waves/SIMD. (c) R6's spilling batched stage reverted to transient loads;
//     weight pipelining (b2 at top, bfr prefetch) kept.

#define LN_EPS 1e-5f
#define NMODES 16
#define FROW 4096     // per-row F/f size: 16k * 2 * 128
#define HROW 16384    // per (b,m) h row: 128*128

typedef __attribute__((ext_vector_type(8))) short short8;
typedef __attribute__((ext_vector_type(8))) ushort ushort8;
typedef __attribute__((ext_vector_type(4))) short short4v;
typedef __attribute__((ext_vector_type(4))) float f32x4;

__device__ __forceinline__ ushort f2bf(float f) {
    unsigned u = __float_as_uint(f);
    unsigned r = (u + 0x7FFFu + ((u >> 16) & 1u)) >> 16;   // RNE
    return (ushort)r;
}
__device__ __forceinline__ float bf2f(ushort h) {
    return __uint_as_float(((unsigned)h) << 16);
}

// ---------------- tables ----------------
__global__ void k_setup(float* __restrict__ Tc, float* __restrict__ Ts,
                        float* __restrict__ IT) {
    const float invs = 0.08838834764831845f;  // 1/sqrt(128)
    for (int idx = threadIdx.x; idx < NMODES * 128; idx += blockDim.x) {
        int k = idx >> 7, n = idx & 127;
        int p = (k * n) & 127;                 // periodic reduction
        float th = (float)p * (6.283185307179586f / 128.0f);
        float c = cosf(th), s = sinf(th);
        Tc[idx] = c * invs;                    // forward: (1/sqrtN) cos
        Ts[idx] = -s * invs;                   // forward: -(1/sqrtN) sin
        float ck = (k == 0) ? invs : 2.0f * invs;
        IT[n * 32 + 2 * k]     = ck * c;       // inverse: c_k cos
        IT[n * 32 + 2 * k + 1] = -ck * s;      // inverse: -c_k sin
    }
}

// ---------------- packed complex-mix weights, transposed, bf16 hi/lo ----------------
// Layout: [k][op][ip]; value(ip,op): ip<128: (op<128? re : im); ip>=128: (op<128? -im : re)
__global__ void k_wpack(const float* __restrict__ w, ushort* __restrict__ Wph,
                        ushort* __restrict__ Wpl) {
    int idx = blockIdx.x * 256 + threadIdx.x;  // 16*256*256 = 1,048,576
    int k  = idx >> 16;
    int op = (idx >> 8) & 255;
    int ip = idx & 255;
    int i = ip & 127, o = op & 127;
    const float* base = w + (((i << 7) | o) * NMODES + k) * 2;
    float re = base[0], im = base[1];
    float v = (ip < 128) ? ((op < 128) ? re : im)
                         : ((op < 128) ? -im : re);
    ushort hi = f2bf(v);
    ushort lo = f2bf(v - bf2f(hi));
    Wph[idx] = hi;
    Wpl[idx] = lo;
}

// ---------------- bf16 FFN weights (once) ----------------
// w0t[h][k] = w0[k][h]  (512x128 bf16); w1t[o][h] = w1[h][o]  (128x512 bf16)
__global__ __launch_bounds__(256) void k_wcvt(const float* __restrict__ w0,
        const float* __restrict__ w1, ushort* __restrict__ w0t,
        ushort* __restrict__ w1t) {
    int idx = blockIdx.x * 256 + threadIdx.x;   // 65536
    int h = idx >> 7, k = idx & 127;
    w0t[idx] = f2bf(w0[k * 512 + h]);
    int o = idx >> 9, hh = idx & 511;
    w1t[idx] = f2bf(w1[hh * 128 + o]);
}

// ---------------- truncated forward DFT ----------------
__global__ __launch_bounds__(128) void k_fft(const float* __restrict__ x,
        const float* __restrict__ Tc, const float* __restrict__ Ts,
        float* __restrict__ F, int mode) {
    __shared__ float Tc_s[NMODES * 128];
    __shared__ float Ts_s[NMODES * 128];
    for (int e = threadIdx.x; e < NMODES * 128; e += 128) {
        Tc_s[e] = Tc[e];
        Ts_s[e] = Ts[e];
    }
    __syncthreads();
    int row = blockIdx.x;
    int base, ts;
    if (mode == 0) { base = row * HROW; ts = 128; }
    else { base = (row >> 7) * 2097152 + (row & 127) * 128; ts = 16384; }
    int i = threadIdx.x;
    float re[NMODES], im[NMODES];
#pragma unroll
    for (int k = 0; k < NMODES; ++k) { re[k] = 0.f; im[k] = 0.f; }
    for (int tb = 0; tb < 32; ++tb) {
        int t0 = tb * 4;
        float xv0 = x[base + (t0 + 0) * ts + i];
        float xv1 = x[base + (t0 + 1) * ts + i];
        float xv2 = x[base + (t0 + 2) * ts + i];
        float xv3 = x[base + (t0 + 3) * ts + i];
#pragma unroll
        for (int k = 0; k < NMODES; ++k) {
            f32x4 c4 = *(const f32x4*)&Tc_s[k * 128 + t0];
            f32x4 s4 = *(const f32x4*)&Ts_s[k * 128 + t0];
            re[k] += xv0 * c4[0] + xv1 * c4[1] + xv2 * c4[2] + xv3 * c4[3];
            im[k] += xv0 * s4[0] + xv1 * s4[1] + xv2 * s4[2] + xv3 * s4[3];
        }
    }
    float* outp = F + row * FROW;
#pragma unroll
    for (int k = 0; k < NMODES; ++k) {
        outp[k * 256 + i]       = re[k];
        outp[k * 256 + 128 + i] = im[k];
    }
}

// ---------------- per-mode channel mix, bf16x3 MFMA (in-place safe) ----------------
__global__ __launch_bounds__(256) void k_mixm(const float* __restrict__ A,
        const ushort* __restrict__ Wph, const ushort* __restrict__ Wpl,
        float* __restrict__ outF) {
    __shared__ ushort Ah[32 * 264];
    __shared__ ushort Al[32 * 264];
    int tid = threadIdx.x;
    int kt = blockIdx.x & 15;
    int bm0 = (blockIdx.x >> 4) * 32;
    {
        int row = tid >> 3, cg = tid & 7;
        const float* arow = A + (bm0 + row) * FROW + kt * 256 + cg * 32;
        ushort* ah = &Ah[row * 264 + cg * 32];
        ushort* al = &Al[row * 264 + cg * 32];
#pragma unroll
        for (int j = 0; j < 8; ++j) {
            f32x4 v = *(const f32x4*)(arow + j * 4);
            short4v h4, l4;
#pragma unroll
            for (int q = 0; q < 4; ++q) {
                ushort h = f2bf(v[q]);
                h4[q] = (short)h;
                l4[q] = (short)f2bf(v[q] - bf2f(h));
            }
            *(short4v*)(ah + j * 4) = h4;
            *(short4v*)(al + j * 4) = l4;
        }
    }
    __syncthreads();
    int lane = tid & 63, wid = tid >> 6;
    int frow = lane & 15, fk8 = (lane >> 4) * 8, fr4 = (lane >> 4) * 4;
    f32x4 acc[2][4];
#pragma unroll
    for (int a = 0; a < 2; ++a)
#pragma unroll
        for (int c = 0; c < 4; ++c) acc[a][c] = {0.f, 0.f, 0.f, 0.f};
    const ushort* wph = Wph + kt * 65536;
    const ushort* wpl = Wpl + kt * 65536;
#pragma unroll
    for (int kk = 0; kk < 8; ++kk) {
        short8 ah0 = *(const short8*)&Ah[(frow)      * 264 + kk * 32 + fk8];
        short8 ah1 = *(const short8*)&Ah[(16 + frow) * 264 + kk * 32 + fk8];
        short8 al0 = *(const short8*)&Al[(frow)      * 264 + kk * 32 + fk8];
        short8 al1 = *(const short8*)&Al[(16 + frow) * 264 + kk * 32 + fk8];
#pragma unroll
        for (int tc = 0; tc < 4; ++tc) {
            int op = wid * 64 + tc * 16 + frow;
            int base = op * 256 + kk * 32 + fk8;
            short8 wh = *(const short8*)&wph[base];
            short8 wl = *(const short8*)&wpl[base];
            acc[0][tc] = __builtin_amdgcn_mfma_f32_16x16x32_bf16(ah0, wh, acc[0][tc], 0, 0, 0);
            acc[0][tc] = __builtin_amdgcn_mfma_f32_16x16x32_bf16(ah0, wl, acc[0][tc], 0, 0, 0);
            acc[0][tc] = __builtin_amdgcn_mfma_f32_16x16x32_bf16(al0, wh, acc[0][tc], 0, 0, 0);
            acc[1][tc] = __builtin_amdgcn_mfma_f32_16x16x32_bf16(ah1, wh, acc[1][tc], 0, 0, 0);
            acc[1][tc] = __builtin_amdgcn_mfma_f32_16x16x32_bf16(ah1, wl, acc[1][tc], 0, 0, 0);
            acc[1][tc] = __builtin_amdgcn_mfma_f32_16x16x32_bf16(al1, wh, acc[1][tc], 0, 0, 0);
        }
    }
#pragma unroll
    for (int tr = 0; tr < 2; ++tr)
#pragma unroll
        for (int tc = 0; tc < 4; ++tc)
#pragma unroll
            for (int r = 0; r < 4; ++r)
                outF[(bm0 + tr * 16 + fr4 + r) * FROW + kt * 256 + wid * 64 + tc * 16 + frow]
                    = acc[tr][tc][r];
}

// ---------------- inverse DFT ----------------
// mode 0: y-branch, contiguous bf16 write: obf[row*16384 + t*128 + o]
// mode 1: y-branch fallback, f32: h32[row*HROW + ...] = acc
// mode 2: x-branch, fused branch-sum: obf[ix] = bf16(bf16(hyin[ix]) + acc)  (scatter)
// mode 3: x-branch fallback: obf[ix] = bf16(h32[ix] + acc)
__global__ __launch_bounds__(256) void k_icdft(const float* __restrict__ f,
        const float* __restrict__ IT, ushort* __restrict__ obf,
        float* __restrict__ h32, const ushort* __restrict__ hyin, int mode) {
    __shared__ float IT_s[128 * 32];
    __shared__ float f_s[32 * 128];
    int row = blockIdx.x;
    for (int e = threadIdx.x; e < 4096; e += 256) {
        IT_s[e] = IT[e];
        f_s[e]  = f[row * FROW + e];
    }
    __syncthreads();
    int o = threadIdx.x & 127, nh = threadIdx.x >> 7;
    for (int nb = 0; nb < 8; ++nb) {
        int n0 = nh * 64 + nb * 8;
        float acc[8];
#pragma unroll
        for (int j = 0; j < 8; ++j) acc[j] = 0.f;
#pragma unroll
        for (int kpb = 0; kpb < 8; ++kpb) {
            int kp0 = kpb * 4;
            float f0 = f_s[kp0 * 128 + o];
            float f1v = f_s[kp0 * 128 + 128 + o];
            float f2v = f_s[kp0 * 128 + 256 + o];
            float f3v = f_s[kp0 * 128 + 384 + o];
#pragma unroll
            for (int j = 0; j < 8; ++j) {
                f32x4 it = *(const f32x4*)&IT_s[(n0 + j) * 32 + kp0];
                acc[j] += f0 * it[0] + f1v * it[1] + f2v * it[2] + f3v * it[3];
            }
        }
        if (mode == 0) {
#pragma unroll
            for (int j = 0; j < 8; ++j)
                obf[row * HROW + (n0 + j) * 128 + o] = f2bf(acc[j]);
        } else if (mode == 1) {
#pragma unroll
            for (int j = 0; j < 8; ++j)
                h32[row * HROW + (n0 + j) * 128 + o] = acc[j];
        } else if (mode == 2) {
#pragma unroll
            for (int j = 0; j < 8; ++j) {
                int ix = (row >> 7) * 2097152 + (row & 127) * 128 + o + (n0 + j) * 16384;
                obf[ix] = f2bf(bf2f(hyin[ix]) + acc[j]);
            }
        } else {
#pragma unroll
            for (int j = 0; j < 8; ++j) {
                int ix = (row >> 7) * 2097152 + (row & 127) * 128 + o + (n0 + j) * 16384;
                obf[ix] = f2bf(h32[ix] + acc[j]);
            }
        }
    }
}

// ---------------- fused FFN + LayerNorm: 1-wave blocks, swizzled 20KB LDS ----------------
// Each 64-lane wave owns 64 rows. Stage = pure copy of pre-summed bf16 hin.
// 16 chunks of 32 hidden: [issue b2] -> GEMM1 -> h1 -> [prefetch bfr] -> GEMM2.
// XOR-swizzled LDS: h_s[64][128] (chunk^=(row&7)), h1[64][32] (chunk^=(row&3)).
__global__ __launch_bounds__(64, 2) void k_ffn(const ushort* __restrict__ hin,
        float* __restrict__ out,
        const ushort* __restrict__ w0t, const float* __restrict__ b0,
        const ushort* __restrict__ w1t, const float* __restrict__ b1,
        const float* __restrict__ g, const float* __restrict__ bb) {
    __shared__ __align__(16) char h_raw[16384];   // [64][128] bf16, swizzled
    __shared__ __align__(16) char h1_raw[4096];   // [64][32]  bf16, swizzled
    int lane = threadIdx.x;
    int R0 = blockIdx.x * 64;

    {   // coalesced stage with swizzled LDS writes (transient regs only)
        const ushort* src = hin + (size_t)R0 * 128;
#pragma unroll 4
        for (int i = 0; i < 16; ++i) {
            int e = lane + i * 64;
            int rl = e >> 4, c8 = e & 15;
            ushort8 v = *(const ushort8*)(src + rl * 128 + c8 * 8);
            *(ushort8*)(h_raw + rl * 256 + ((c8 ^ (rl & 7)) << 4)) = v;
        }
    }
    __syncthreads();

    int frow = lane & 15, qg = lane >> 4;
    int fk8 = qg * 8, fr4 = qg * 4;
    int sw7 = frow & 7;     // h_s row-swizzle bits (row&7 == frow&7)
    int sw3 = frow & 3;     // h1 row-swizzle bits (row&3 == frow&3)

    f32x4 acc2[4][8];
#pragma unroll
    for (int a = 0; a < 4; ++a)
#pragma unroll
        for (int c = 0; c < 8; ++c) acc2[a][c] = {0.f, 0.f, 0.f, 0.f};

    // prologue: GEMM1 weight frags for chunk 0
    short8 bfr[2][4];
#pragma unroll
    for (int tc2 = 0; tc2 < 2; ++tc2)
#pragma unroll
        for (int kk = 0; kk < 4; ++kk)
            bfr[tc2][kk] = *(const short8*)&w0t[(tc2 * 16 + frow) * 128 + kk * 32 + fk8];

#pragma unroll 1
    for (int ch = 0; ch < 16; ++ch) {
        // issue GEMM2 weight frags now; GEMM1 covers their latency
        short8 b2[8];
#pragma unroll
        for (int tc = 0; tc < 8; ++tc)
            b2[tc] = *(const short8*)&w1t[(tc * 16 + frow) * 512 + ch * 32 + fk8];
        float b0v0 = b0[ch * 32 + frow];
        float b0v1 = b0[ch * 32 + 16 + frow];

        // ---- GEMM1: 64 rows x 32 hidden, K=128 (two tr-groups) ----
#pragma unroll
        for (int g2 = 0; g2 < 2; ++g2) {
            f32x4 acc1[2][2];
#pragma unroll
            for (int a = 0; a < 2; ++a)
#pragma unroll
                for (int c = 0; c < 2; ++c) acc1[a][c] = {0.f, 0.f, 0.f, 0.f};
#pragma unroll
            for (int kk = 0; kk < 4; ++kk)
#pragma unroll
                for (int t2 = 0; t2 < 2; ++t2) {
                    int row = (g2 * 2 + t2) * 16 + frow;
                    short8 av = *(const short8*)(h_raw + row * 256
                                 + (((kk * 4 + qg) ^ sw7) << 4));
                    acc1[t2][0] = __builtin_amdgcn_mfma_f32_16x16x32_bf16(
                        av, bfr[0][kk], acc1[t2][0], 0, 0, 0);
                    acc1[t2][1] = __builtin_amdgcn_mfma_f32_16x16x32_bf16(
                        av, bfr[1][kk], acc1[t2][1], 0, 0, 0);
                }
#pragma unroll
            for (int t2 = 0; t2 < 2; ++t2)
#pragma unroll
                for (int r = 0; r < 4; ++r) {
                    int rowl = (g2 * 2 + t2) * 16 + fr4 + r;   // rowl&3 == r
                    *(ushort*)(h1_raw + rowl * 64 + ((frow * 2) ^ (r << 4))) =
                        f2bf(fmaxf(acc1[t2][0][r] + b0v0, 0.f));
                    *(ushort*)(h1_raw + rowl * 64 + (((16 + frow) * 2) ^ (r << 4))) =
                        f2bf(fmaxf(acc1[t2][1][r] + b0v1, 0.f));
                }
        }

        // prefetch next chunk's GEMM1 frags; GEMM2 covers their latency
        if (ch < 15) {
#pragma unroll
            for (int tc2 = 0; tc2 < 2; ++tc2)
#pragma unroll
                for (int kk = 0; kk < 4; ++kk)
                    bfr[tc2][kk] = *(const short8*)
                        &w0t[((ch + 1) * 32 + tc2 * 16 + frow) * 128 + kk * 32 + fk8];
        }

        // ---- GEMM2 K-step: 64 rows x 128 out, K=32 ----
#pragma unroll
        for (int tr = 0; tr < 4; ++tr) {
            int row = tr * 16 + frow;
            short8 a2 = *(const short8*)(h1_raw + row * 64 + ((qg ^ sw3) << 4));
#pragma unroll
            for (int tc = 0; tc < 8; ++tc)
                acc2[tr][tc] = __builtin_amdgcn_mfma_f32_16x16x32_bf16(
                    a2, b2[tc], acc2[tr][tc], 0, 0, 0);
        }
    }

    // ---- epilogue: +b1, in-register LN, direct stores ----
    float b1v[8], gv[8], bv[8];
#pragma unroll
    for (int tc = 0; tc < 8; ++tc) {
        int o = tc * 16 + frow;
        b1v[tc] = b1[o]; gv[tc] = g[o]; bv[tc] = bb[o];
    }
#pragma unroll
    for (int tr = 0; tr < 4; ++tr)
#pragma unroll
        for (int r = 0; r < 4; ++r) {
            float s = 0.f, qq = 0.f;
#pragma unroll
            for (int tc = 0; tc < 8; ++tc) {
                float v = acc2[tr][tc][r] + b1v[tc];
                acc2[tr][tc][r] = v;
                s += v; qq += v * v;
            }
            s += __shfl_xor(s, 1); qq += __shfl_xor(qq, 1);
            s += __shfl_xor(s, 2); qq += __shfl_xor(qq, 2);
            s += __shfl_xor(s, 4); qq += __shfl_xor(qq, 4);
            s += __shfl_xor(s, 8); qq += __shfl_xor(qq, 8);
            float mu = s * (1.0f / 128.0f);
            float var = qq * (1.0f / 128.0f) - mu * mu;
            float rs = rsqrtf(fmaxf(var, 0.f) + LN_EPS);
            float* orow = &out[(size_t)(R0 + tr * 16 + fr4 + r) * 128];
#pragma unroll
            for (int tc = 0; tc < 8; ++tc)
                orow[tc * 16 + frow] = (acc2[tr][tc][r] - mu) * rs * gv[tc] + bv[tc];
        }
}

extern "C" void kernel_launch(void* const* d_in, const int* in_sizes, int n_in,
                              void* d_out, int out_size, void* d_ws, size_t ws_size,
                              hipStream_t stream) {
    (void)in_sizes; (void)n_in; (void)out_size;
    const float* x   = (const float*)d_in[0];
    const float* w1  = (const float*)d_in[1];
    const float* w2  = (const float*)d_in[2];
    const float* fw0 = (const float*)d_in[3];
    const float* fb0 = (const float*)d_in[4];
    const float* fw1 = (const float*)d_in[5];
    const float* fb1 = (const float*)d_in[6];
    const float* lng = (const float*)d_in[7];
    const float* lnb = (const float*)d_in[8];
    float* out = (float*)d_out;

    char* ws = (char*)d_ws;
    float*  Tc  = (float*)(ws);
    float*  Ts  = (float*)(ws + 8192);
    float*  IT  = (float*)(ws + 16384);
    ushort* Wph = (ushort*)(ws + 32768);                  // 2 MB
    ushort* Wpl = (ushort*)(ws + 32768 + 2097152);        // 2 MB
    ushort* w0t = (ushort*)(ws + 4227072);                // 128 KB
    ushort* w1t = (ushort*)(ws + 4358144);                // 128 KB
    float*  buf0 = (float*)(ws + 4489216);                // F/f (33.5 MB, in-place mix)
    ushort* hy   = (ushort*)(ws + 38043648);              // 67 MB
    ushort* hsum = (ushort*)(ws + 105152512);             // 67 MB
    const size_t need_two = 172261376ull;
    int two = (ws_size >= need_two) ? 1 : 0;
    ushort* hbfs = hy;   // fallback single-buffer (105.2 MB)

    k_setup<<<1, 256, 0, stream>>>(Tc, Ts, IT);
    k_wcvt <<<256, 256, 0, stream>>>(fw0, fw1, w0t, w1t);

    // y-branch: DFT over n, mix with w1, inverse over n -> hy[b,m,n,o] bf16
    k_wpack<<<4096, 256, 0, stream>>>(w1, Wph, Wpl);
    k_fft  <<<2048, 128, 0, stream>>>(x, Tc, Ts, buf0, 0);
    k_mixm <<<1024, 256, 0, stream>>>(buf0, Wph, Wpl, buf0);
    if (two) k_icdft<<<2048, 256, 0, stream>>>(buf0, IT, hy, out, hy, 0);
    else     k_icdft<<<2048, 256, 0, stream>>>(buf0, IT, hy, out, hy, 1);

    // x-branch: DFT over m, mix with w2, inverse over m; fused h = hy + hx -> hsum
    k_wpack<<<4096, 256, 0, stream>>>(w2, Wph, Wpl);
    k_fft  <<<2048, 128, 0, stream>>>(x, Tc, Ts, buf0, 1);
    k_mixm <<<1024, 256, 0, stream>>>(buf0, Wph, Wpl, buf0);
    if (two) k_icdft<<<2048, 256, 0, stream>>>(buf0, IT, hsum, out, hy, 2);
    else     k_icdft<<<2048, 256, 0, stream>>>(buf0, IT, hbfs, out, hy, 3);

    // fused FFN + LayerNorm -> d_out (1-wave blocks, 20KB swizzled LDS)
    k_ffn<<<4096, 64, 0, stream>>>(two ? hsum : hbfs, out,
                                   w0t, fb0, w1t, fb1, lng, lnb);
}

// Round 8
// 492.530 us; speedup vs baseline: 1.2269x; 1.1153x over previous
//
#include <hip/hip_runtime.h>

// Geo-FFNO forward: factored Fourier (DFT -> per-mode complex mix -> iDFT, 16 modes)
// + fused FFN (Linear 128->512, ReLU, Linear 512->128, +bias, LayerNorm).
// B=16, M=N=128, D=I=O=128, NM=16, H=512.
//
// R8: k_ffn -> 2-wave blocks, output cols split across waves (acc2[4][4]=64 regs,
// no spill at launch_bounds(128,3)). Shared double-buffered h1 (80 B rows, ~2-way
// banks) + ONE raw s_barrier per chunk draining lgkmcnt only (vmcnt prefetch of
// next chunk's w0 frags survives the barrier). Cross-wave LN via 1KB LDS partials.

#define LN_EPS 1e-5f
#define NMODES 16
#define FROW 4096     // per-row F/f size: 16k * 2 * 128
#define HROW 16384    // per (b,m) h row: 128*128

typedef __attribute__((ext_vector_type(8))) short short8;
typedef __attribute__((ext_vector_type(8))) ushort ushort8;
typedef __attribute__((ext_vector_type(4))) short short4v;
typedef __attribute__((ext_vector_type(4))) float f32x4;

__device__ __forceinline__ ushort f2bf(float f) {
    unsigned u = __float_as_uint(f);
    unsigned r = (u + 0x7FFFu + ((u >> 16) & 1u)) >> 16;   // RNE
    return (ushort)r;
}
__device__ __forceinline__ float bf2f(ushort h) {
    return __uint_as_float(((unsigned)h) << 16);
}

// ---------------- tables ----------------
__global__ void k_setup(float* __restrict__ Tc, float* __restrict__ Ts,
                        float* __restrict__ IT) {
    const float invs = 0.08838834764831845f;  // 1/sqrt(128)
    for (int idx = threadIdx.x; idx < NMODES * 128; idx += blockDim.x) {
        int k = idx >> 7, n = idx & 127;
        int p = (k * n) & 127;                 // periodic reduction
        float th = (float)p * (6.283185307179586f / 128.0f);
        float c = cosf(th), s = sinf(th);
        Tc[idx] = c * invs;                    // forward: (1/sqrtN) cos
        Ts[idx] = -s * invs;                   // forward: -(1/sqrtN) sin
        float ck = (k == 0) ? invs : 2.0f * invs;
        IT[n * 32 + 2 * k]     = ck * c;       // inverse: c_k cos
        IT[n * 32 + 2 * k + 1] = -ck * s;      // inverse: -c_k sin
    }
}

// ---------------- packed complex-mix weights, transposed, bf16 hi/lo ----------------
// Layout: [k][op][ip]; value(ip,op): ip<128: (op<128? re : im); ip>=128: (op<128? -im : re)
__global__ void k_wpack(const float* __restrict__ w, ushort* __restrict__ Wph,
                        ushort* __restrict__ Wpl) {
    int idx = blockIdx.x * 256 + threadIdx.x;  // 16*256*256 = 1,048,576
    int k  = idx >> 16;
    int op = (idx >> 8) & 255;
    int ip = idx & 255;
    int i = ip & 127, o = op & 127;
    const float* base = w + (((i << 7) | o) * NMODES + k) * 2;
    float re = base[0], im = base[1];
    float v = (ip < 128) ? ((op < 128) ? re : im)
                         : ((op < 128) ? -im : re);
    ushort hi = f2bf(v);
    ushort lo = f2bf(v - bf2f(hi));
    Wph[idx] = hi;
    Wpl[idx] = lo;
}

// ---------------- bf16 FFN weights (once) ----------------
// w0t[h][k] = w0[k][h]  (512x128 bf16); w1t[o][h] = w1[h][o]  (128x512 bf16)
__global__ __launch_bounds__(256) void k_wcvt(const float* __restrict__ w0,
        const float* __restrict__ w1, ushort* __restrict__ w0t,
        ushort* __restrict__ w1t) {
    int idx = blockIdx.x * 256 + threadIdx.x;   // 65536
    int h = idx >> 7, k = idx & 127;
    w0t[idx] = f2bf(w0[k * 512 + h]);
    int o = idx >> 9, hh = idx & 511;
    w1t[idx] = f2bf(w1[hh * 128 + o]);
}

// ---------------- truncated forward DFT ----------------
__global__ __launch_bounds__(128) void k_fft(const float* __restrict__ x,
        const float* __restrict__ Tc, const float* __restrict__ Ts,
        float* __restrict__ F, int mode) {
    __shared__ float Tc_s[NMODES * 128];
    __shared__ float Ts_s[NMODES * 128];
    for (int e = threadIdx.x; e < NMODES * 128; e += 128) {
        Tc_s[e] = Tc[e];
        Ts_s[e] = Ts[e];
    }
    __syncthreads();
    int row = blockIdx.x;
    int base, ts;
    if (mode == 0) { base = row * HROW; ts = 128; }
    else { base = (row >> 7) * 2097152 + (row & 127) * 128; ts = 16384; }
    int i = threadIdx.x;
    float re[NMODES], im[NMODES];
#pragma unroll
    for (int k = 0; k < NMODES; ++k) { re[k] = 0.f; im[k] = 0.f; }
    for (int tb = 0; tb < 32; ++tb) {
        int t0 = tb * 4;
        float xv0 = x[base + (t0 + 0) * ts + i];
        float xv1 = x[base + (t0 + 1) * ts + i];
        float xv2 = x[base + (t0 + 2) * ts + i];
        float xv3 = x[base + (t0 + 3) * ts + i];
#pragma unroll
        for (int k = 0; k < NMODES; ++k) {
            f32x4 c4 = *(const f32x4*)&Tc_s[k * 128 + t0];
            f32x4 s4 = *(const f32x4*)&Ts_s[k * 128 + t0];
            re[k] += xv0 * c4[0] + xv1 * c4[1] + xv2 * c4[2] + xv3 * c4[3];
            im[k] += xv0 * s4[0] + xv1 * s4[1] + xv2 * s4[2] + xv3 * s4[3];
        }
    }
    float* outp = F + row * FROW;
#pragma unroll
    for (int k = 0; k < NMODES; ++k) {
        outp[k * 256 + i]       = re[k];
        outp[k * 256 + 128 + i] = im[k];
    }
}

// ---------------- per-mode channel mix, bf16x3 MFMA (in-place safe) ----------------
__global__ __launch_bounds__(256) void k_mixm(const float* __restrict__ A,
        const ushort* __restrict__ Wph, const ushort* __restrict__ Wpl,
        float* __restrict__ outF) {
    __shared__ ushort Ah[32 * 264];
    __shared__ ushort Al[32 * 264];
    int tid = threadIdx.x;
    int kt = blockIdx.x & 15;
    int bm0 = (blockIdx.x >> 4) * 32;
    {
        int row = tid >> 3, cg = tid & 7;
        const float* arow = A + (bm0 + row) * FROW + kt * 256 + cg * 32;
        ushort* ah = &Ah[row * 264 + cg * 32];
        ushort* al = &Al[row * 264 + cg * 32];
#pragma unroll
        for (int j = 0; j < 8; ++j) {
            f32x4 v = *(const f32x4*)(arow + j * 4);
            short4v h4, l4;
#pragma unroll
            for (int q = 0; q < 4; ++q) {
                ushort h = f2bf(v[q]);
                h4[q] = (short)h;
                l4[q] = (short)f2bf(v[q] - bf2f(h));
            }
            *(short4v*)(ah + j * 4) = h4;
            *(short4v*)(al + j * 4) = l4;
        }
    }
    __syncthreads();
    int lane = tid & 63, wid = tid >> 6;
    int frow = lane & 15, fk8 = (lane >> 4) * 8, fr4 = (lane >> 4) * 4;
    f32x4 acc[2][4];
#pragma unroll
    for (int a = 0; a < 2; ++a)
#pragma unroll
        for (int c = 0; c < 4; ++c) acc[a][c] = {0.f, 0.f, 0.f, 0.f};
    const ushort* wph = Wph + kt * 65536;
    const ushort* wpl = Wpl + kt * 65536;
#pragma unroll
    for (int kk = 0; kk < 8; ++kk) {
        short8 ah0 = *(const short8*)&Ah[(frow)      * 264 + kk * 32 + fk8];
        short8 ah1 = *(const short8*)&Ah[(16 + frow) * 264 + kk * 32 + fk8];
        short8 al0 = *(const short8*)&Al[(frow)      * 264 + kk * 32 + fk8];
        short8 al1 = *(const short8*)&Al[(16 + frow) * 264 + kk * 32 + fk8];
#pragma unroll
        for (int tc = 0; tc < 4; ++tc) {
            int op = wid * 64 + tc * 16 + frow;
            int base = op * 256 + kk * 32 + fk8;
            short8 wh = *(const short8*)&wph[base];
            short8 wl = *(const short8*)&wpl[base];
            acc[0][tc] = __builtin_amdgcn_mfma_f32_16x16x32_bf16(ah0, wh, acc[0][tc], 0, 0, 0);
            acc[0][tc] = __builtin_amdgcn_mfma_f32_16x16x32_bf16(ah0, wl, acc[0][tc], 0, 0, 0);
            acc[0][tc] = __builtin_amdgcn_mfma_f32_16x16x32_bf16(al0, wh, acc[0][tc], 0, 0, 0);
            acc[1][tc] = __builtin_amdgcn_mfma_f32_16x16x32_bf16(ah1, wh, acc[1][tc], 0, 0, 0);
            acc[1][tc] = __builtin_amdgcn_mfma_f32_16x16x32_bf16(ah1, wl, acc[1][tc], 0, 0, 0);
            acc[1][tc] = __builtin_amdgcn_mfma_f32_16x16x32_bf16(al1, wh, acc[1][tc], 0, 0, 0);
        }
    }
#pragma unroll
    for (int tr = 0; tr < 2; ++tr)
#pragma unroll
        for (int tc = 0; tc < 4; ++tc)
#pragma unroll
            for (int r = 0; r < 4; ++r)
                outF[(bm0 + tr * 16 + fr4 + r) * FROW + kt * 256 + wid * 64 + tc * 16 + frow]
                    = acc[tr][tc][r];
}

// ---------------- inverse DFT ----------------
// mode 0: y-branch, contiguous bf16 write: obf[row*16384 + t*128 + o]
// mode 1: y-branch fallback, f32: h32[row*HROW + ...] = acc
// mode 2: x-branch, fused branch-sum: obf[ix] = bf16(bf16(hyin[ix]) + acc)  (scatter)
// mode 3: x-branch fallback: obf[ix] = bf16(h32[ix] + acc)
__global__ __launch_bounds__(256) void k_icdft(const float* __restrict__ f,
        const float* __restrict__ IT, ushort* __restrict__ obf,
        float* __restrict__ h32, const ushort* __restrict__ hyin, int mode) {
    __shared__ float IT_s[128 * 32];
    __shared__ float f_s[32 * 128];
    int row = blockIdx.x;
    for (int e = threadIdx.x; e < 4096; e += 256) {
        IT_s[e] = IT[e];
        f_s[e]  = f[row * FROW + e];
    }
    __syncthreads();
    int o = threadIdx.x & 127, nh = threadIdx.x >> 7;
    for (int nb = 0; nb < 8; ++nb) {
        int n0 = nh * 64 + nb * 8;
        float acc[8];
#pragma unroll
        for (int j = 0; j < 8; ++j) acc[j] = 0.f;
#pragma unroll
        for (int kpb = 0; kpb < 8; ++kpb) {
            int kp0 = kpb * 4;
            float f0 = f_s[kp0 * 128 + o];
            float f1v = f_s[kp0 * 128 + 128 + o];
            float f2v = f_s[kp0 * 128 + 256 + o];
            float f3v = f_s[kp0 * 128 + 384 + o];
#pragma unroll
            for (int j = 0; j < 8; ++j) {
                f32x4 it = *(const f32x4*)&IT_s[(n0 + j) * 32 + kp0];
                acc[j] += f0 * it[0] + f1v * it[1] + f2v * it[2] + f3v * it[3];
            }
        }
        if (mode == 0) {
#pragma unroll
            for (int j = 0; j < 8; ++j)
                obf[row * HROW + (n0 + j) * 128 + o] = f2bf(acc[j]);
        } else if (mode == 1) {
#pragma unroll
            for (int j = 0; j < 8; ++j)
                h32[row * HROW + (n0 + j) * 128 + o] = acc[j];
        } else if (mode == 2) {
#pragma unroll
            for (int j = 0; j < 8; ++j) {
                int ix = (row >> 7) * 2097152 + (row & 127) * 128 + o + (n0 + j) * 16384;
                obf[ix] = f2bf(bf2f(hyin[ix]) + acc[j]);
            }
        } else {
#pragma unroll
            for (int j = 0; j < 8; ++j) {
                int ix = (row >> 7) * 2097152 + (row & 127) * 128 + o + (n0 + j) * 16384;
                obf[ix] = f2bf(h32[ix] + acc[j]);
            }
        }
    }
}

// ---------------- fused FFN + LayerNorm: 2-wave blocks, split output cols ----------------
// 64 rows/block. Wave w: GEMM1 for hidden cols [ch*32+w*16, +16); GEMM2 for out cols
// [w*64, +64). Shared dbuf h1 (80 B rows); ONE raw s_barrier/chunk (lgkmcnt drain only,
// vmcnt prefetch survives). acc2[4][4]=64 regs -> no spill at launch_bounds(128,3).
__global__ __launch_bounds__(128, 3) void k_ffn(const ushort* __restrict__ hin,
        float* __restrict__ out,
        const ushort* __restrict__ w0t, const float* __restrict__ b0,
        const ushort* __restrict__ w1t, const float* __restrict__ b1,
        const float* __restrict__ g, const float* __restrict__ bb) {
    __shared__ __align__(16) char h_raw[16384];      // [64][128] bf16, swizzled c8^=(rl&7)
    __shared__ __align__(16) char h1_raw[2][5120];   // dbuf: 64 rows x 80 B (64 data + 16 pad)
    __shared__ float ps_s[128];                      // [wave][row] LN partial sums
    __shared__ float pq_s[128];
    int tid = threadIdx.x;
    int wave = tid >> 6, lane = tid & 63;
    int R0 = blockIdx.x * 64;

    {   // coalesced stage, swizzled LDS writes (transient regs)
        const ushort* src = hin + (size_t)R0 * 128;
#pragma unroll
        for (int i = 0; i < 8; ++i) {
            int e = tid + i * 128;
            int rl = e >> 4, c8 = e & 15;
            ushort8 v = *(const ushort8*)(src + rl * 128 + c8 * 8);
            *(ushort8*)(h_raw + rl * 256 + ((c8 ^ (rl & 7)) << 4)) = v;
        }
    }
    __syncthreads();

    int frow = lane & 15, qg = lane >> 4;
    int fk8 = qg * 8, fr4 = qg * 4;
    int sw7 = frow & 7;

    f32x4 acc2[4][4];
#pragma unroll
    for (int a = 0; a < 4; ++a)
#pragma unroll
        for (int c = 0; c < 4; ++c) acc2[a][c] = {0.f, 0.f, 0.f, 0.f};

    // prologue: GEMM1 weight frags (wave's 16 hidden cols of chunk 0)
    short8 bfr[4];
#pragma unroll
    for (int kk = 0; kk < 4; ++kk)
        bfr[kk] = *(const short8*)&w0t[(wave * 16 + frow) * 128 + kk * 32 + fk8];

#pragma unroll 1
    for (int ch = 0; ch < 16; ++ch) {
        // GEMM2 weight frags for this chunk (wave's 64 out cols); GEMM1 covers latency
        short8 b2[4];
#pragma unroll
        for (int tc = 0; tc < 4; ++tc)
            b2[tc] = *(const short8*)&w1t[(wave * 64 + tc * 16 + frow) * 512 + ch * 32 + fk8];
        float b0v = b0[ch * 32 + wave * 16 + frow];

        // ---- GEMM1: 64 rows x 16 hidden (this wave's half), K=128 ----
        f32x4 acc1[4];
#pragma unroll
        for (int a = 0; a < 4; ++a) acc1[a] = {0.f, 0.f, 0.f, 0.f};
#pragma unroll
        for (int kk = 0; kk < 4; ++kk)
#pragma unroll
            for (int tr = 0; tr < 4; ++tr) {
                short8 av = *(const short8*)(h_raw + (tr * 16 + frow) * 256
                             + (((kk * 4 + qg) ^ sw7) << 4));
                acc1[tr] = __builtin_amdgcn_mfma_f32_16x16x32_bf16(
                    av, bfr[kk], acc1[tr], 0, 0, 0);
            }
        char* h1w = h1_raw[ch & 1];
#pragma unroll
        for (int tr = 0; tr < 4; ++tr)
#pragma unroll
            for (int r = 0; r < 4; ++r)
                *(ushort*)(h1w + (tr * 16 + fr4 + r) * 80 + wave * 32 + frow * 2) =
                    f2bf(fmaxf(acc1[tr][r] + b0v, 0.f));

        // prefetch next chunk's GEMM1 frags; raw barrier below won't drain vmcnt
        if (ch < 15) {
#pragma unroll
            for (int kk = 0; kk < 4; ++kk)
                bfr[kk] = *(const short8*)
                    &w0t[((ch + 1) * 32 + wave * 16 + frow) * 128 + kk * 32 + fk8];
        }

        // cross-wave h1 visibility: drain LDS only, keep vmcnt in flight
        asm volatile("s_waitcnt lgkmcnt(0)" ::: "memory");
        __builtin_amdgcn_s_barrier();
        asm volatile("" ::: "memory");

        // ---- GEMM2: 64 rows x 64 out (this wave's half), K=32 ----
#pragma unroll
        for (int tr = 0; tr < 4; ++tr) {
            short8 a2 = *(const short8*)(h1w + (tr * 16 + frow) * 80 + qg * 16);
#pragma unroll
            for (int tc = 0; tc < 4; ++tc)
                acc2[tr][tc] = __builtin_amdgcn_mfma_f32_16x16x32_bf16(
                    a2, b2[tc], acc2[tr][tc], 0, 0, 0);
        }
        // dbuf: next chunk's GEMM1 writes the other buffer; no second barrier needed
    }

    // ---- epilogue: +b1, per-wave LN partials, cross-wave combine, stores ----
    float b1v[4], gv[4], bv[4];
#pragma unroll
    for (int tc = 0; tc < 4; ++tc) {
        int o = wave * 64 + tc * 16 + frow;
        b1v[tc] = b1[o]; gv[tc] = g[o]; bv[tc] = bb[o];
    }
#pragma unroll
    for (int tr = 0; tr < 4; ++tr)
#pragma unroll
        for (int r = 0; r < 4; ++r) {
            float s = 0.f, qq = 0.f;
#pragma unroll
            for (int tc = 0; tc < 4; ++tc) {
                float v = acc2[tr][tc][r] + b1v[tc];
                acc2[tr][tc][r] = v;
                s += v; qq += v * v;
            }
            s += __shfl_xor(s, 1); qq += __shfl_xor(qq, 1);
            s += __shfl_xor(s, 2); qq += __shfl_xor(qq, 2);
            s += __shfl_xor(s, 4); qq += __shfl_xor(qq, 4);
            s += __shfl_xor(s, 8); qq += __shfl_xor(qq, 8);
            if (frow == 0) {
                int row = tr * 16 + fr4 + r;
                ps_s[wave * 64 + row] = s;
                pq_s[wave * 64 + row] = qq;
            }
        }
    __syncthreads();
#pragma unroll
    for (int tr = 0; tr < 4; ++tr)
#pragma unroll
        for (int r = 0; r < 4; ++r) {
            int row = tr * 16 + fr4 + r;
            float S = ps_s[row] + ps_s[64 + row];
            float Q = pq_s[row] + pq_s[64 + row];
            float mu = S * (1.0f / 128.0f);
            float var = Q * (1.0f / 128.0f) - mu * mu;
            float rs = rsqrtf(fmaxf(var, 0.f) + LN_EPS);
            float* orow = &out[(size_t)(R0 + row) * 128 + wave * 64];
#pragma unroll
            for (int tc = 0; tc < 4; ++tc)
                orow[tc * 16 + frow] = (acc2[tr][tc][r] - mu) * rs * gv[tc] + bv[tc];
        }
}

extern "C" void kernel_launch(void* const* d_in, const int* in_sizes, int n_in,
                              void* d_out, int out_size, void* d_ws, size_t ws_size,
                              hipStream_t stream) {
    (void)in_sizes; (void)n_in; (void)out_size;
    const float* x   = (const float*)d_in[0];
    const float* w1  = (const float*)d_in[1];
    const float* w2  = (const float*)d_in[2];
    const float* fw0 = (const float*)d_in[3];
    const float* fb0 = (const float*)d_in[4];
    const float* fw1 = (const float*)d_in[5];
    const float* fb1 = (const float*)d_in[6];
    const float* lng = (const float*)d_in[7];
    const float* lnb = (const float*)d_in[8];
    float* out = (float*)d_out;

    char* ws = (char*)d_ws;
    float*  Tc  = (float*)(ws);
    float*  Ts  = (float*)(ws + 8192);
    float*  IT  = (float*)(ws + 16384);
    ushort* Wph = (ushort*)(ws + 32768);                  // 2 MB
    ushort* Wpl = (ushort*)(ws + 32768 + 2097152);        // 2 MB
    ushort* w0t = (ushort*)(ws + 4227072);                // 128 KB
    ushort* w1t = (ushort*)(ws + 4358144);                // 128 KB
    float*  buf0 = (float*)(ws + 4489216);                // F/f (33.5 MB, in-place mix)
    ushort* hy   = (ushort*)(ws + 38043648);              // 67 MB
    ushort* hsum = (ushort*)(ws + 105152512);             // 67 MB
    const size_t need_two = 172261376ull;
    int two = (ws_size >= need_two) ? 1 : 0;
    ushort* hbfs = hy;   // fallback single-buffer (105.2 MB)

    k_setup<<<1, 256, 0, stream>>>(Tc, Ts, IT);
    k_wcvt <<<256, 256, 0, stream>>>(fw0, fw1, w0t, w1t);

    // y-branch: DFT over n, mix with w1, inverse over n -> hy[b,m,n,o] bf16
    k_wpack<<<4096, 256, 0, stream>>>(w1, Wph, Wpl);
    k_fft  <<<2048, 128, 0, stream>>>(x, Tc, Ts, buf0, 0);
    k_mixm <<<1024, 256, 0, stream>>>(buf0, Wph, Wpl, buf0);
    if (two) k_icdft<<<2048, 256, 0, stream>>>(buf0, IT, hy, out, hy, 0);
    else     k_icdft<<<2048, 256, 0, stream>>>(buf0, IT, hy, out, hy, 1);

    // x-branch: DFT over m, mix with w2, inverse over m; fused h = hy + hx -> hsum
    k_wpack<<<4096, 256, 0, stream>>>(w2, Wph, Wpl);
    k_fft  <<<2048, 128, 0, stream>>>(x, Tc, Ts, buf0, 1);
    k_mixm <<<1024, 256, 0, stream>>>(buf0, Wph, Wpl, buf0);
    if (two) k_icdft<<<2048, 256, 0, stream>>>(buf0, IT, hsum, out, hy, 2);
    else     k_icdft<<<2048, 256, 0, stream>>>(buf0, IT, hbfs, out, hy, 3);

    // fused FFN + LayerNorm -> d_out (2-wave blocks)
    k_ffn<<<4096, 128, 0, stream>>>(two ? hsum : hbfs, out,
                                    w0t, fb0, w1t, fb1, lng, lnb);
}